// Round 5
// baseline (2353.020 us; speedup 1.0000x reference)
//
#include <hip/hip_runtime.h>
#include <hip/hip_bf16.h>

#define NROWS 4096    // B*S
#define DDIM  1024
#define MKEYS 32768
#define HDIM  128
#define KSEL  16

// ---- sims MFMA GEMM geometry: 256x256 tile, 8 waves, 8-phase half-tile pipeline ----
#define SBM 256            // rows per block
#define SBN 256            // keys per block
#define SNKB (MKEYS / SBN) // 128 key blocks
#define CANDS_PER_ROW (SNKB * KSEL)   // 2048
#define NSTEPS 48          // 3 segments x 16 K-tiles of 64

typedef short bf16x8 __attribute__((ext_vector_type(8)));
typedef float f32x4  __attribute__((ext_vector_type(4)));

__device__ __forceinline__ float bf2f(unsigned short u) {
    union { unsigned int i; float f; } x; x.i = ((unsigned int)u) << 16; return x.f;
}
__device__ __forceinline__ unsigned short f2bf(float f) {
    union { float f; unsigned int u; } v; v.f = f;
    unsigned int r = (v.u + 0x7fffu + ((v.u >> 16) & 1u)) >> 16;   // RNE
    return (unsigned short)r;
}
__device__ __forceinline__ void gload16(const void* g, const void* l) {
    __builtin_amdgcn_global_load_lds((const __attribute__((address_space(1))) unsigned int*)g,
                                     (__attribute__((address_space(3))) unsigned int*)l, 16, 0, 0);
}
__device__ __forceinline__ void vmw8() { asm volatile("s_waitcnt vmcnt(8)" ::: "memory"); }
__device__ __forceinline__ void vmw6() { asm volatile("s_waitcnt vmcnt(6)" ::: "memory"); }
__device__ __forceinline__ void vmw2() { asm volatile("s_waitcnt vmcnt(2)" ::: "memory"); }
__device__ __forceinline__ void vmw0() { asm volatile("s_waitcnt vmcnt(0)" ::: "memory"); }
// sorted-descending top-16 insertion, fully static indexing (no scratch)
__device__ __forceinline__ void ins16(float v, int id, float* lv, int* li) {
    if (v > lv[15]) {
#pragma unroll
        for (int i = 0; i < 16; ++i) {
            const bool gt = v > lv[i];
            const float tv = gt ? lv[i] : v;
            const int   ti = gt ? li[i] : id;
            if (gt) { lv[i] = v; li[i] = id; }
            v = tv; id = ti;
        }
    }
}
// trunc-hi / RNE-lo split of two fp32 -> packed bf16 pair words
__device__ __forceinline__ void split2(float x0, float x1, unsigned int& hp, unsigned int& lp) {
    union { float f; unsigned int u; } u0, u1;
    u0.f = x0; u1.f = x1;
    hp = (u0.u >> 16) | (u1.u & 0xffff0000u);
    const float r0 = x0 - bf2f((unsigned short)(u0.u >> 16));
    const float r1 = x1 - bf2f((unsigned short)(u1.u >> 16));
    lp = (unsigned int)f2bf(r0) | ((unsigned int)f2bf(r1) << 16);
}

// ---------------- Kernel 0: fp32 -> (hi, lo) bf16 split ----------------
__global__ __launch_bounds__(256)
void split_bf16_kernel(const float* __restrict__ x, unsigned short* __restrict__ hi,
                       unsigned short* __restrict__ lo, const int n4)
{
    int i = blockIdx.x * 256 + threadIdx.x;
    const int stride = gridDim.x * 256;
    for (; i < n4; i += stride) {
        const float4 f = ((const float4*)x)[i];
        ushort4 h, l;
        h.x = f2bf(f.x); l.x = f2bf(f.x - bf2f(h.x));
        h.y = f2bf(f.y); l.y = f2bf(f.y - bf2f(h.y));
        h.z = f2bf(f.z); l.z = f2bf(f.z - bf2f(h.z));
        h.w = f2bf(f.w); l.w = f2bf(f.w - bf2f(h.w));
        ((ushort4*)hi)[i] = h;
        ((ushort4*)lo)[i] = l;
    }
}

// ---------------- Kernel A: sims = Q.K^T, 8-phase pipelined MFMA + fused top-16 ----------------
// LDS: A half-slots 4x16KB @0; B half-slots 4x16KB @64KB. Half h of tile t -> slot (t&1)*2+h.
// Phase p computes block-quadrant: P1:(A0,B0) P2:(A1,B0) P3:(A1,B1) P4:(A0,B1); per wave
// (2Mx4N grid) 16 MFMA/phase into acc[quadrant][mi][ni]. Stages: P1:A0(t+1) P2:B1(t+1)
// P3:B0(t+2) P4:A1(t+2); waits: vmcnt(8)@P2-close, vmcnt(6)@P4-close (3 halves in flight).
__global__ __launch_bounds__(512, 2)
void sims_mfma_kernel(const unsigned short* __restrict__ Qhi, const unsigned short* __restrict__ Qlo,
                      const unsigned short* __restrict__ Khi, const unsigned short* __restrict__ Klo,
                      float* __restrict__ cand_val, int* __restrict__ cand_idx)
{
    __shared__ char smem[131072];
    const int tid  = threadIdx.x;
    const int lane = tid & 63;
    const int w    = tid >> 6;
    const int wr2  = w >> 2;          // 0..1 row sub-block within quadrant
    const int wc4  = w & 3;           // 0..3 col sub-block within quadrant
    const int row0 = blockIdx.x * SBM;
    const int key0 = blockIdx.y * SBN;

    const f32x4 zero = {0.f, 0.f, 0.f, 0.f};
    f32x4 acc[4][4][2];               // [quadrant][mi][ni]
#pragma unroll
    for (int q = 0; q < 4; ++q)
#pragma unroll
        for (int mi = 0; mi < 4; ++mi)
#pragma unroll
            for (int ni = 0; ni < 2; ++ni) acc[q][mi][ni] = zero;

    const int srow = lane >> 3;                       // row within 8-row chunk
    const int scol = (((lane & 7) ^ srow) << 4);      // pre-swizzled source byte col

    // stage one 16KB half: kind 0=A(Q),1=B(K); h in {0,1}; s = K-tile index
    auto STAGE = [&](int kind, int h, int s) {
        const int seg   = s >> 4;
        const int kbyte = (s & 15) << 7;
        const unsigned short* base;
        int g0;
        if (kind == 0) { base = (seg == 1) ? Qlo : Qhi; g0 = row0 + (h << 7); }
        else           { base = (seg == 2) ? Klo : Khi; g0 = key0 + (h << 7); }
        char* dst = smem + (kind << 16) + (((((s & 1) << 1) + h)) << 14);
#pragma unroll
        for (int r8 = 0; r8 < 2; ++r8) {
            const int chunk = w + (r8 << 3);          // 0..15, wave-uniform
            const int r = (chunk << 3) + srow;        // 0..127 within half
            const char* src = (const char*)base + (((size_t)(g0 + r)) << 11) + kbyte + scol;
            gload16(src, dst + (chunk << 10));
        }
    };
    auto LDA = [&](int tp, int qm, int mi, int kk) -> bf16x8 {
        const int rr = (wr2 << 6) + (mi << 4) + (lane & 15);          // 0..127
        const char* p = smem + (((tp << 1) + qm) << 14)
                      + rr * 128 + ((((kk << 6) + ((lane >> 4) << 4))) ^ ((rr & 7) << 4));
        return *(const bf16x8*)p;
    };
    auto LDB = [&](int tp, int qn, int ni, int kk) -> bf16x8 {
        const int rr = (wc4 << 5) + (ni << 4) + (lane & 15);          // 0..127
        const char* p = smem + 65536 + (((tp << 1) + qn) << 14)
                      + rr * 128 + ((((kk << 6) + ((lane >> 4) << 4))) ^ ((rr & 7) << 4));
        return *(const bf16x8*)p;
    };

#define SPHASE(QI, QM, QN, SKIND, SHALF, STILE, SEN, CLOSEN)                     \
    {                                                                             \
        bf16x8 a_[4][2], b_[2][2];                                                \
        _Pragma("unroll") for (int mi_ = 0; mi_ < 4; ++mi_)                       \
            _Pragma("unroll") for (int kk_ = 0; kk_ < 2; ++kk_)                   \
                a_[mi_][kk_] = LDA(tp, QM, mi_, kk_);                             \
        _Pragma("unroll") for (int ni_ = 0; ni_ < 2; ++ni_)                       \
            _Pragma("unroll") for (int kk_ = 0; kk_ < 2; ++kk_)                   \
                b_[ni_][kk_] = LDB(tp, QN, ni_, kk_);                             \
        if (SEN) STAGE(SKIND, SHALF, STILE);                                      \
        __builtin_amdgcn_s_barrier();                                             \
        __builtin_amdgcn_s_setprio(1);                                            \
        _Pragma("unroll") for (int mi_ = 0; mi_ < 4; ++mi_)                       \
            _Pragma("unroll") for (int ni_ = 0; ni_ < 2; ++ni_)                   \
                _Pragma("unroll") for (int kk_ = 0; kk_ < 2; ++kk_)               \
                    acc[QI][mi_][ni_] = __builtin_amdgcn_mfma_f32_16x16x32_bf16(  \
                        a_[mi_][kk_], b_[ni_][kk_], acc[QI][mi_][ni_], 0, 0, 0);  \
        __builtin_amdgcn_s_setprio(0);                                            \
        const int cn_ = (CLOSEN);                                                 \
        if (cn_ == 8) vmw8(); else if (cn_ == 6) vmw6();                          \
        else if (cn_ == 2) vmw2(); else if (cn_ == 0) vmw0();                     \
        __builtin_amdgcn_s_barrier();                                             \
    }

    // prologue: 6 halves in stream order, then force oldest 3 (tile 0 ready except B1)
    STAGE(1, 0, 0);   // B0(0)
    STAGE(0, 1, 0);   // A1(0)
    STAGE(0, 0, 0);   // A0(0)
    STAGE(1, 1, 0);   // B1(0)
    STAGE(1, 0, 1);   // B0(1)
    STAGE(0, 1, 1);   // A1(1)
    vmw6();
    __builtin_amdgcn_s_barrier();

#pragma unroll 1
    for (int t = 0; t < NSTEPS; ++t) {
        const int tp = t & 1;
        SPHASE(0, 0, 0, 0, 0, t + 1, (t < NSTEPS - 1), -1)
        SPHASE(1, 1, 0, 1, 1, t + 1, (t < NSTEPS - 1), (t < NSTEPS - 1 ? 8 : 0))
        SPHASE(2, 1, 1, 1, 0, t + 2, (t < NSTEPS - 2), -1)
        SPHASE(3, 0, 1, 0, 1, t + 2, (t < NSTEPS - 2),
               (t < NSTEPS - 2 ? 6 : (t == NSTEPS - 2 ? 2 : -1)))
    }
#undef SPHASE

    // ---- fused top-16 epilogue: 4 passes of 64 cols through LDS C tile [256][68] ----
    float lv[16]; int li[16];
#pragma unroll
    for (int i = 0; i < 16; ++i) { lv[i] = -3.4e38f; li[i] = 0; }
    float* C_lds = (float*)smem;

#pragma unroll
    for (int cpass = 0; cpass < 4; ++cpass) {
        __syncthreads();
        if ((wc4 >> 1) == (cpass & 1)) {
            const int qn = cpass >> 1;
#pragma unroll
            for (int qm = 0; qm < 2; ++qm) {
                const int qi = (qn == 0) ? qm : (3 - qm);   // P-order (0,0),(1,0),(1,1),(0,1)
#pragma unroll
                for (int mi = 0; mi < 4; ++mi)
#pragma unroll
                    for (int ni = 0; ni < 2; ++ni) {
                        const int r = (qm << 7) + (wr2 << 6) + (mi << 4) + ((lane >> 4) << 2);
                        const int c = ((wc4 & 1) << 5) + (ni << 4) + (lane & 15);
                        const f32x4 v = acc[qi][mi][ni];
#pragma unroll
                        for (int j = 0; j < 4; ++j) C_lds[(r + j) * 68 + c] = v[j];
                    }
            }
        }
        __syncthreads();
        if (tid < 256) {
            const int gbase = key0 + (cpass << 6);
#pragma unroll 1
            for (int c4 = 0; c4 < 16; ++c4) {
                const float4 vv = *(const float4*)&C_lds[tid * 68 + (c4 << 2)];
                const float thr = lv[15];
                if (vv.x > thr || vv.y > thr || vv.z > thr || vv.w > thr) {
                    ins16(vv.x, gbase + c4 * 4 + 0, lv, li);
                    ins16(vv.y, gbase + c4 * 4 + 1, lv, li);
                    ins16(vv.z, gbase + c4 * 4 + 2, lv, li);
                    ins16(vv.w, gbase + c4 * 4 + 3, lv, li);
                }
            }
        }
    }
    if (tid < 256) {
        const size_t o = (((size_t)(row0 + tid)) * SNKB + blockIdx.y) * KSEL;
#pragma unroll
        for (int i = 0; i < 16; ++i) { cand_val[o + i] = lv[i]; cand_idx[o + i] = li[i]; }
    }
}

// ---------------- Kernel B: merge 128 blocks x 16 candidates -> global top-16 per row ----------------
__global__ __launch_bounds__(256)
void topk_merge_kernel(const float* __restrict__ cand_val, const int* __restrict__ cand_idx,
                       int* __restrict__ topk)
{
    const int row  = blockIdx.x * 4 + (threadIdx.x >> 6);
    const int lane = threadIdx.x & 63;
    const size_t base = (size_t)row * CANDS_PER_ROW;
    float lv[16]; int li[16];
#pragma unroll
    for (int i = 0; i < 16; ++i) { lv[i] = -3.4e38f; li[i] = 0x7fffffff; }
#pragma unroll 1
    for (int m = 0; m < CANDS_PER_ROW / 64; ++m) {                // 32 per lane
        const int p = lane + (m << 6);
        ins16(cand_val[base + p], cand_idx[base + p], lv, li);
    }
    int out = 0;
#pragma unroll 1
    for (int it = 0; it < KSEL; ++it) {
        float rv = lv[0]; int ridx = li[0];
#pragma unroll
        for (int off = 1; off < 64; off <<= 1) {
            const float ov = __shfl_xor(rv, off);
            const int   oi = __shfl_xor(ridx, off);
            if (ov > rv || (ov == rv && oi < ridx)) { rv = ov; ridx = oi; }
        }
        if (lane == it) out = ridx;
        if (li[0] == ridx) {
#pragma unroll
            for (int i = 0; i < 15; ++i) { lv[i] = lv[i + 1]; li[i] = li[i + 1]; }
            lv[15] = -3.4e38f; li[15] = 0x7fffffff;
        }
    }
    if (lane < KSEL) topk[(size_t)row * KSEL + lane] = out;
}

// ---------------- Kernel C: projections via split-bf16 MFMA (unchanged, known-good) ----------------
__global__ __launch_bounds__(256)
void proj_split_kernel(const float* __restrict__ X, const unsigned short* __restrict__ Whi,
                       const unsigned short* __restrict__ Wlo, const float* __restrict__ bias,
                       void* __restrict__ outp, const int store_bf16)
{
    __shared__ char smem[65536];
    const int tid  = threadIdx.x;
    const int lane = tid & 63;
    const int w    = tid >> 6;
    const int wr   = w >> 1, wc = w & 1;
    const int row0 = blockIdx.x * 128;
    const int col0 = blockIdx.y * 128;

    const f32x4 zero = {0.f, 0.f, 0.f, 0.f};
    f32x4 acc[4][4];
#pragma unroll
    for (int mi = 0; mi < 4; ++mi)
#pragma unroll
        for (int ni = 0; ni < 4; ++ni) acc[mi][ni] = zero;

    const int srow = lane >> 3;
    const int scol = (((lane & 7) ^ srow) << 4);
    const int xr = tid >> 1, xh = tid & 1;

    for (int step = 0; step < 16; ++step) {
        const int kbyte = step << 7;
        const int k0    = step << 6;
        __syncthreads();
#pragma unroll
        for (int i = 0; i < 8; ++i) {
            const int chunk = w + (i << 2);
            const int plane = chunk >> 4;
            const int r     = ((chunk & 15) << 3) + srow;
            const unsigned short* Wb = plane ? Wlo : Whi;
            const char* src = (const char*)Wb + (((size_t)(col0 + r)) << 11) + kbyte + scol;
            gload16(src, smem + 32768 + (chunk << 10));
        }
        {
            const float* Xp = X + (size_t)(row0 + xr) * DDIM + k0 + xh * 32;
            float4 xa[8];
#pragma unroll
            for (int i = 0; i < 8; ++i) xa[i] = ((const float4*)Xp)[i];
            const int xbase = xr * 128;
#pragma unroll
            for (int s4 = 0; s4 < 4; ++s4) {
                const float4 a = xa[2 * s4], b = xa[2 * s4 + 1];
                uint4 hw, lw;
                split2(a.x, a.y, hw.x, lw.x);
                split2(a.z, a.w, hw.y, lw.y);
                split2(b.x, b.y, hw.z, lw.z);
                split2(b.z, b.w, hw.w, lw.w);
                const int off = xbase + ((((xh << 2) + s4) ^ (xr & 7)) << 4);
                *(uint4*)(smem + off)         = hw;
                *(uint4*)(smem + 16384 + off) = lw;
            }
        }
        asm volatile("s_waitcnt vmcnt(0)" ::: "memory");
        __syncthreads();
#pragma unroll
        for (int kk = 0; kk < 2; ++kk) {
            const int cb = (kk << 6) + ((lane >> 4) << 4);
            bf16x8 ah[4], bh[4];
#pragma unroll
            for (int mi = 0; mi < 4; ++mi) {
                const int r = wr * 64 + mi * 16 + (lane & 15);
                ah[mi] = *(const bf16x8*)(smem + r * 128 + (cb ^ ((r & 7) << 4)));
            }
#pragma unroll
            for (int ni = 0; ni < 4; ++ni) {
                const int r = wc * 64 + ni * 16 + (lane & 15);
                bh[ni] = *(const bf16x8*)(smem + 32768 + r * 128 + (cb ^ ((r & 7) << 4)));
            }
#pragma unroll
            for (int mi = 0; mi < 4; ++mi)
#pragma unroll
                for (int ni = 0; ni < 4; ++ni)
                    acc[mi][ni] = __builtin_amdgcn_mfma_f32_16x16x32_bf16(ah[mi], bh[ni], acc[mi][ni], 0, 0, 0);
            bf16x8 al[4];
#pragma unroll
            for (int mi = 0; mi < 4; ++mi) {
                const int r = wr * 64 + mi * 16 + (lane & 15);
                al[mi] = *(const bf16x8*)(smem + 16384 + r * 128 + (cb ^ ((r & 7) << 4)));
            }
#pragma unroll
            for (int mi = 0; mi < 4; ++mi)
#pragma unroll
                for (int ni = 0; ni < 4; ++ni)
                    acc[mi][ni] = __builtin_amdgcn_mfma_f32_16x16x32_bf16(al[mi], bh[ni], acc[mi][ni], 0, 0, 0);
            bf16x8 bl[4];
#pragma unroll
            for (int ni = 0; ni < 4; ++ni) {
                const int r = wc * 64 + ni * 16 + (lane & 15);
                bl[ni] = *(const bf16x8*)(smem + 49152 + r * 128 + (cb ^ ((r & 7) << 4)));
            }
#pragma unroll
            for (int mi = 0; mi < 4; ++mi)
#pragma unroll
                for (int ni = 0; ni < 4; ++ni)
                    acc[mi][ni] = __builtin_amdgcn_mfma_f32_16x16x32_bf16(ah[mi], bl[ni], acc[mi][ni], 0, 0, 0);
        }
    }

#pragma unroll
    for (int ni = 0; ni < 4; ++ni) {
        const int col = col0 + wc * 64 + ni * 16 + (lane & 15);
        const float bz = bias[col];
#pragma unroll
        for (int mi = 0; mi < 4; ++mi) {
            const int rbase = row0 + wr * 64 + mi * 16 + ((lane >> 4) << 2);
            const f32x4 v = acc[mi][ni];
#pragma unroll
            for (int j = 0; j < 4; ++j) {
                const float val = v[j] + bz;
                if (store_bf16)
                    ((unsigned short*)outp)[(size_t)(rbase + j) * DDIM + col] = f2bf(val);
                else
                    ((float*)outp)[(size_t)(rbase + j) * DDIM + col] = val;
            }
        }
    }
}

// ---------------- Kernel D: per-token 8-head attention over 16 retrieved slots ----------------
__global__ __launch_bounds__(256)
void attn_kernel(const float* __restrict__ Qp, const __hip_bfloat16* __restrict__ Kp,
                 const __hip_bfloat16* __restrict__ Vp, const int* __restrict__ topk,
                 float* __restrict__ attn_out)
{
    const int t = blockIdx.x;
    __shared__ int   idx_s[KSEL];
    __shared__ float sc_s[4][KSEL];
    if (threadIdx.x < KSEL) idx_s[threadIdx.x] = topk[(size_t)t * KSEL + threadIdx.x];
    __syncthreads();
    const int wv   = threadIdx.x >> 6;
    const int lane = threadIdx.x & 63;
    const int jj = lane >> 2, p = lane & 3;
    const float scale = 0.08838834764831845f;  // 1/sqrt(128)
    const unsigned short* Kpu = (const unsigned short*)Kp;
    const unsigned short* Vpu = (const unsigned short*)Vp;

#pragma unroll 1
    for (int hh = 0; hh < 2; ++hh) {
        const int h = wv * 2 + hh;
        const float* qh = Qp + (size_t)t * DDIM + h * HDIM + p * 32;
        const unsigned short* krow = Kpu + (size_t)idx_s[jj] * DDIM + h * HDIM + p * 32;
        float s = 0.f;
#pragma unroll
        for (int u = 0; u < 32; u += 8) {
            uint4  kv = *(const uint4*)(krow + u);
            float4 qa = *(const float4*)(qh + u);
            float4 qb = *(const float4*)(qh + u + 4);
            const unsigned short* kk = (const unsigned short*)&kv;
            s += bf2f(kk[0]) * qa.x + bf2f(kk[1]) * qa.y + bf2f(kk[2]) * qa.z + bf2f(kk[3]) * qa.w
               + bf2f(kk[4]) * qb.x + bf2f(kk[5]) * qb.y + bf2f(kk[6]) * qb.z + bf2f(kk[7]) * qb.w;
        }
        s += __shfl_xor(s, 1);
        s += __shfl_xor(s, 2);
        if (p == 0) sc_s[wv][jj] = s * scale;
        __syncthreads();
        float mx = -__builtin_inff();
#pragma unroll
        for (int n = 0; n < KSEL; ++n) mx = fmaxf(mx, sc_s[wv][n]);
        float wj[KSEL]; float wsum = 0.f;
#pragma unroll
        for (int n = 0; n < KSEL; ++n) { wj[n] = __expf(sc_s[wv][n] - mx); wsum += wj[n]; }
        const float inv = 1.f / wsum;
        const int d = lane * 2;
        float o0 = 0.f, o1 = 0.f;
#pragma unroll
        for (int n = 0; n < KSEL; ++n) {
            const unsigned int vv = *(const unsigned int*)(Vpu + (size_t)idx_s[n] * DDIM + h * HDIM + d);
            const float w = wj[n] * inv;
            o0 += w * bf2f((unsigned short)(vv & 0xffffu));
            o1 += w * bf2f((unsigned short)(vv >> 16));
        }
        *(float2*)(attn_out + (size_t)t * DDIM + h * HDIM + d) = make_float2(o0, o1);
        __syncthreads();
    }
}

extern "C" void kernel_launch(void* const* d_in, const int* in_sizes, int n_in,
                              void* d_out, int out_size, void* d_ws, size_t ws_size,
                              hipStream_t stream)
{
    const float* queries = (const float*)d_in[0];
    const float* mkeys   = (const float*)d_in[1];
    const float* mvals   = (const float*)d_in[2];
    const float* ipw     = (const float*)d_in[3];
    const float* ipb     = (const float*)d_in[4];
    const float* opw     = (const float*)d_in[5];
    const float* opb     = (const float*)d_in[6];

    char* ws = (char*)d_ws;
    size_t off = 0;
    auto alloc = [&](size_t bytes) -> char* {
        char* p = ws + off;
        off += (bytes + 255) & ~(size_t)255;
        return p;
    };
    unsigned short* Khi = (unsigned short*)alloc((size_t)MKEYS * DDIM * 2);   // 67.1 MB
    unsigned short* Klo = (unsigned short*)alloc((size_t)MKEYS * DDIM * 2);   // 67.1 MB
    unsigned short* Qhi = (unsigned short*)alloc((size_t)NROWS * DDIM * 2);   // 8.4 MB
    unsigned short* Qlo = (unsigned short*)alloc((size_t)NROWS * DDIM * 2);   // 8.4 MB
    unsigned short* IPhi = (unsigned short*)alloc((size_t)3 * DDIM * DDIM * 2); // 6.3 MB
    unsigned short* IPlo = (unsigned short*)alloc((size_t)3 * DDIM * DDIM * 2); // 6.3 MB
    unsigned short* OPhi = (unsigned short*)alloc((size_t)DDIM * DDIM * 2);     // 2.1 MB
    unsigned short* OPlo = (unsigned short*)alloc((size_t)DDIM * DDIM * 2);     // 2.1 MB
    float* cand_val = (float*)alloc((size_t)NROWS * CANDS_PER_ROW * 4);       // 33.5 MB
    int*   cand_idx = (int*)  alloc((size_t)NROWS * CANDS_PER_ROW * 4);       // 33.5 MB
    int*   topk     = (int*)  alloc((size_t)NROWS * KSEL * 4);                // 0.26 MB
    // stream-ordered aliases (total ws ~235 MB):
    float* Qp       = (float*)cand_val;            // written after merge
    float* attn_out = (float*)cand_idx;            // written by attn (after merge)
    __hip_bfloat16* Kp = (__hip_bfloat16*)Khi;     // Khi/Klo dead after sims
    __hip_bfloat16* Vp = (__hip_bfloat16*)Klo;

    // 0) splits: sims operands + weights
    split_bf16_kernel<<<2048, 256, 0, stream>>>(queries, Qhi, Qlo, NROWS * DDIM / 4);
    split_bf16_kernel<<<2048, 256, 0, stream>>>(mkeys, Khi, Klo, MKEYS * DDIM / 4);
    split_bf16_kernel<<<1024, 256, 0, stream>>>(ipw, IPhi, IPlo, 3 * DDIM * DDIM / 4);
    split_bf16_kernel<<<512,  256, 0, stream>>>(opw, OPhi, OPlo, DDIM * DDIM / 4);
    // 1) similarity GEMM (8-phase split-bf16 MFMA) + per-keyblock top-16
    sims_mfma_kernel<<<dim3(NROWS / SBM, MKEYS / SBN), 512, 0, stream>>>(Qhi, Qlo, Khi, Klo, cand_val, cand_idx);
    // 2) merge to global top-16 indices
    topk_merge_kernel<<<NROWS / 4, 256, 0, stream>>>(cand_val, cand_idx, topk);
    // 3) projections (split-bf16 MFMA): q (f32 out), memory bank through Wk/Wv (bf16 out)
    proj_split_kernel<<<dim3(NROWS / 128, 8), 256, 0, stream>>>(queries, IPhi, IPlo, ipb, Qp, 0);
    proj_split_kernel<<<dim3(MKEYS / 128, 8), 256, 0, stream>>>(mkeys, IPhi + (size_t)DDIM * DDIM,
                                                                IPlo + (size_t)DDIM * DDIM, ipb + DDIM, Kp, 1);
    proj_split_kernel<<<dim3(MKEYS / 128, 8), 256, 0, stream>>>(mvals, IPhi + 2 * (size_t)DDIM * DDIM,
                                                                IPlo + 2 * (size_t)DDIM * DDIM, ipb + 2 * DDIM, Vp, 1);
    // 4) gather + attention
    attn_kernel<<<NROWS, 256, 0, stream>>>(Qp, Kp, Vp, topk, attn_out);
    // 5) output projection -> d_out (f32)
    proj_split_kernel<<<dim3(NROWS / 128, 8), 256, 0, stream>>>(attn_out, OPhi, OPlo, opb, d_out, 0);
}

// Round 6
// 1769.200 us; speedup vs baseline: 1.3300x; 1.3300x over previous
//
#include <hip/hip_runtime.h>
#include <hip/hip_bf16.h>

#define NROWS 4096    // B*S
#define DDIM  1024
#define MKEYS 32768
#define HDIM  128
#define KSEL  16
#define NCAND 32      // rescored candidates per row

// ---- sims MFMA GEMM geometry: 256x256 tile, 8 waves, double-buffered, bf16-hi only ----
#define SBM 256
#define SBN 256
#define SNKB (MKEYS / SBN) // 128 key blocks
#define CANDS_PER_ROW (SNKB * KSEL)   // 2048
#define NSTEPS 16          // K = 1024, hi plane only

typedef short bf16x8 __attribute__((ext_vector_type(8)));
typedef float f32x4  __attribute__((ext_vector_type(4)));

__device__ __forceinline__ float bf2f(unsigned short u) {
    union { unsigned int i; float f; } x; x.i = ((unsigned int)u) << 16; return x.f;
}
__device__ __forceinline__ unsigned short f2bf(float f) {
    union { float f; unsigned int u; } v; v.f = f;
    unsigned int r = (v.u + 0x7fffu + ((v.u >> 16) & 1u)) >> 16;   // RNE
    return (unsigned short)r;
}
__device__ __forceinline__ void gload16(const void* g, const void* l) {
    __builtin_amdgcn_global_load_lds((const __attribute__((address_space(1))) unsigned int*)g,
                                     (__attribute__((address_space(3))) unsigned int*)l, 16, 0, 0);
}
// sorted-descending top-N insertion, fully static indexing (no scratch)
template <int N>
__device__ __forceinline__ void insN(float v, int id, float* lv, int* li) {
    if (v > lv[N - 1]) {
#pragma unroll
        for (int i = 0; i < N; ++i) {
            const bool gt = v > lv[i];
            const float tv = gt ? lv[i] : v;
            const int   ti = gt ? li[i] : id;
            if (gt) { lv[i] = v; li[i] = id; }
            v = tv; id = ti;
        }
    }
}
// trunc-hi / RNE-lo split of two fp32 -> packed bf16 pair words
__device__ __forceinline__ void split2(float x0, float x1, unsigned int& hp, unsigned int& lp) {
    union { float f; unsigned int u; } u0, u1;
    u0.f = x0; u1.f = x1;
    hp = (u0.u >> 16) | (u1.u & 0xffff0000u);
    const float r0 = x0 - bf2f((unsigned short)(u0.u >> 16));
    const float r1 = x1 - bf2f((unsigned short)(u1.u >> 16));
    lp = (unsigned int)f2bf(r0) | ((unsigned int)f2bf(r1) << 16);
}

// ---------------- Kernel 0a: fp32 -> bf16 (RNE, hi only) ----------------
__global__ __launch_bounds__(256)
void conv_bf16_kernel(const float* __restrict__ x, unsigned short* __restrict__ hi, const int n4)
{
    int i = blockIdx.x * 256 + threadIdx.x;
    const int stride = gridDim.x * 256;
    for (; i < n4; i += stride) {
        const float4 f = ((const float4*)x)[i];
        ushort4 h;
        h.x = f2bf(f.x); h.y = f2bf(f.y); h.z = f2bf(f.z); h.w = f2bf(f.w);
        ((ushort4*)hi)[i] = h;
    }
}

// ---------------- Kernel 0b: fp32 -> (hi, lo) bf16 split (weights) ----------------
__global__ __launch_bounds__(256)
void split_bf16_kernel(const float* __restrict__ x, unsigned short* __restrict__ hi,
                       unsigned short* __restrict__ lo, const int n4)
{
    int i = blockIdx.x * 256 + threadIdx.x;
    const int stride = gridDim.x * 256;
    for (; i < n4; i += stride) {
        const float4 f = ((const float4*)x)[i];
        ushort4 h, l;
        h.x = f2bf(f.x); l.x = f2bf(f.x - bf2f(h.x));
        h.y = f2bf(f.y); l.y = f2bf(f.y - bf2f(h.y));
        h.z = f2bf(f.z); l.z = f2bf(f.z - bf2f(h.z));
        h.w = f2bf(f.w); l.w = f2bf(f.w - bf2f(h.w));
        ((ushort4*)hi)[i] = h;
        ((ushort4*)lo)[i] = l;
    }
}

// ---------------- Kernel A: sims(bf16) = Qhi.Khi^T, 256x256 dbuf counted-vmcnt + fused top-16 ----------------
// Structure identical to the measured round-4 kernel; only the lo/hi segment logic removed (NSTEPS=16).
__global__ __launch_bounds__(512, 2)
void sims_mfma_kernel(const unsigned short* __restrict__ Qhi, const unsigned short* __restrict__ Khi,
                      float* __restrict__ cand_val, int* __restrict__ cand_idx)
{
    __shared__ char smem[131072];
    const int tid  = threadIdx.x;
    const int lane = tid & 63;
    const int w    = tid >> 6;
    const int wrow = w >> 2, wcol = w & 3;
    const int row0 = blockIdx.x * SBM;
    const int key0 = blockIdx.y * SBN;

    const f32x4 zero = {0.f, 0.f, 0.f, 0.f};
    f32x4 acc[8][4];
#pragma unroll
    for (int mi = 0; mi < 8; ++mi)
#pragma unroll
        for (int ni = 0; ni < 4; ++ni) acc[mi][ni] = zero;

    const int srow = lane >> 3;
    const int scol = (((lane & 7) ^ srow) << 4);

    auto STAGE = [&](int b, int s) {
        const int kbyte = s << 7;                                 // 128B per K-step
        char* dst = smem + (b << 16);
#pragma unroll
        for (int i = 0; i < 8; ++i) {
            const int chunk = w + (i << 3);                       // 0..63, wave-uniform
            const char* src;
            if (chunk < 32) {                                     // A: rows 0..255
                const int r = (chunk << 3) + srow;
                src = (const char*)Qhi + (((size_t)(row0 + r)) << 11) + kbyte + scol;
            } else {                                              // B: keys 0..255
                const int r = ((chunk - 32) << 3) + srow;
                src = (const char*)Khi + (((size_t)(key0 + r)) << 11) + kbyte + scol;
            }
            gload16(src, dst + (chunk << 10));
        }
    };

    STAGE(0, 0);
    int cur = 0;
#pragma unroll 1
    for (int step = 0; step < NSTEPS; ++step) {
        if (step + 1 < NSTEPS) {
            STAGE(cur ^ 1, step + 1);
            asm volatile("s_waitcnt vmcnt(8)\n\ts_barrier" ::: "memory");
        } else {
            asm volatile("s_waitcnt vmcnt(0)\n\ts_barrier" ::: "memory");
        }
        const char* Abuf = smem + (cur << 16);
        const char* Bbuf = Abuf + 32768;
#pragma unroll
        for (int kk = 0; kk < 2; ++kk) {
            const int cb = (kk << 6) + ((lane >> 4) << 4);
            bf16x8 af[8], bf[4];
#pragma unroll
            for (int mi = 0; mi < 8; ++mi) {
                const int r = wrow * 128 + mi * 16 + (lane & 15);
                af[mi] = *(const bf16x8*)(Abuf + r * 128 + (cb ^ ((r & 7) << 4)));
            }
#pragma unroll
            for (int ni = 0; ni < 4; ++ni) {
                const int r = wcol * 64 + ni * 16 + (lane & 15);
                bf[ni] = *(const bf16x8*)(Bbuf + r * 128 + (cb ^ ((r & 7) << 4)));
            }
#pragma unroll
            for (int mi = 0; mi < 8; ++mi)
#pragma unroll
                for (int ni = 0; ni < 4; ++ni)
                    acc[mi][ni] = __builtin_amdgcn_mfma_f32_16x16x32_bf16(af[mi], bf[ni], acc[mi][ni], 0, 0, 0);
        }
        asm volatile("s_waitcnt lgkmcnt(0)\n\ts_barrier" ::: "memory");
        cur ^= 1;
    }

    // ---- fused top-16 epilogue: 4 passes of 64 cols through LDS C tile [256][68] f32 ----
    float lv[16]; int li[16];
#pragma unroll
    for (int i = 0; i < 16; ++i) { lv[i] = -3.4e38f; li[i] = 0; }
    float* C_lds = (float*)smem;

#pragma unroll
    for (int q = 0; q < 4; ++q) {
        __syncthreads();
        if (wcol == q) {
#pragma unroll
            for (int mi = 0; mi < 8; ++mi)
#pragma unroll
                for (int ni = 0; ni < 4; ++ni) {
                    const int r = wrow * 128 + mi * 16 + ((lane >> 4) << 2);
                    const int c = ni * 16 + (lane & 15);
                    const f32x4 v = acc[mi][ni];
#pragma unroll
                    for (int j = 0; j < 4; ++j) C_lds[(r + j) * 68 + c] = v[j];
                }
        }
        __syncthreads();
        if (tid < 256) {
            const int gbase = key0 + (q << 6);
#pragma unroll 1
            for (int c4 = 0; c4 < 16; ++c4) {
                const float4 vv = *(const float4*)&C_lds[tid * 68 + (c4 << 2)];
                const float thr = lv[15];
                if (vv.x > thr || vv.y > thr || vv.z > thr || vv.w > thr) {
                    insN<16>(vv.x, gbase + c4 * 4 + 0, lv, li);
                    insN<16>(vv.y, gbase + c4 * 4 + 1, lv, li);
                    insN<16>(vv.z, gbase + c4 * 4 + 2, lv, li);
                    insN<16>(vv.w, gbase + c4 * 4 + 3, lv, li);
                }
            }
        }
    }
    if (tid < 256) {
        const size_t o = (((size_t)(row0 + tid)) * SNKB + blockIdx.y) * KSEL;
#pragma unroll
        for (int i = 0; i < 16; ++i) { cand_val[o + i] = lv[i]; cand_idx[o + i] = li[i]; }
    }
}

// ---------------- Kernel B: merge 128x16 candidates -> top-32 (bf16 scores) per row ----------------
// Per-lane 32-deep list: provably captures any concentration (global top-32 <= 32 per lane).
__global__ __launch_bounds__(256)
void topk_merge_kernel(const float* __restrict__ cand_val, const int* __restrict__ cand_idx,
                       int* __restrict__ cand32)
{
    const int row  = blockIdx.x * 4 + (threadIdx.x >> 6);
    const int lane = threadIdx.x & 63;
    const size_t base = (size_t)row * CANDS_PER_ROW;
    float lv[NCAND]; int li[NCAND];
#pragma unroll
    for (int i = 0; i < NCAND; ++i) { lv[i] = -3.4e38f; li[i] = 0x7fffffff; }
#pragma unroll 1
    for (int m = 0; m < CANDS_PER_ROW / 64; ++m) {                // 32 per lane
        const int p = lane + (m << 6);
        insN<NCAND>(cand_val[base + p], cand_idx[base + p], lv, li);
    }
    int out = 0;
#pragma unroll 1
    for (int it = 0; it < NCAND; ++it) {
        float rv = lv[0]; int ridx = li[0];
#pragma unroll
        for (int off = 1; off < 64; off <<= 1) {
            const float ov = __shfl_xor(rv, off);
            const int   oi = __shfl_xor(ridx, off);
            if (ov > rv || (ov == rv && oi < ridx)) { rv = ov; ridx = oi; }
        }
        if (lane == it) out = ridx;
        if (li[0] == ridx) {
#pragma unroll
            for (int i = 0; i < NCAND - 1; ++i) { lv[i] = lv[i + 1]; li[i] = li[i + 1]; }
            lv[NCAND - 1] = -3.4e38f; li[NCAND - 1] = 0x7fffffff;
        }
    }
    if (lane < NCAND) cand32[(size_t)row * NCAND + lane] = out;
}

// ---------------- Kernel B2: exact fp32 rescore of 32 candidates -> final top-16 ----------------
// block = row; 4 waves x 8 candidates; 64-lane dot over 1024 dims; wave0 selects top-16
// with reference tie-break (value desc, index asc). Set-selection only (attention is
// permutation-invariant over slots).
__global__ __launch_bounds__(256)
void rescore_kernel(const float* __restrict__ Q, const float* __restrict__ K,
                    const int* __restrict__ cand32, int* __restrict__ topk)
{
    const int row  = blockIdx.x;
    const int wv   = threadIdx.x >> 6;
    const int lane = threadIdx.x & 63;
    __shared__ float sv[NCAND];
    __shared__ int   si[NCAND];
    if (threadIdx.x < NCAND) si[threadIdx.x] = cand32[(size_t)row * NCAND + threadIdx.x];
    // per-lane q fragment (16 elems), loaded once
    float4 qv[4];
#pragma unroll
    for (int u = 0; u < 4; ++u)
        qv[u] = ((const float4*)(Q + (size_t)row * DDIM))[(u << 6) + lane];
    __syncthreads();
#pragma unroll 1
    for (int c = 0; c < 8; ++c) {
        const int slot = wv * 8 + c;
        const float* kr = K + (size_t)si[slot] * DDIM;
        float s = 0.f;
#pragma unroll
        for (int u = 0; u < 4; ++u) {
            const float4 kv = ((const float4*)kr)[(u << 6) + lane];
            s += kv.x * qv[u].x + kv.y * qv[u].y + kv.z * qv[u].z + kv.w * qv[u].w;
        }
#pragma unroll
        for (int off = 32; off >= 1; off >>= 1) s += __shfl_xor(s, off);
        if (lane == 0) sv[slot] = s;
    }
    __syncthreads();
    if (wv == 0) {
        float v = (lane < NCAND) ? sv[lane] : -3.4e38f;
        int  id = (lane < NCAND) ? si[lane] : 0x7fffffff;
        int out = 0;
#pragma unroll 1
        for (int it = 0; it < KSEL; ++it) {
            float rv = v; int ridx = id;
#pragma unroll
            for (int off = 1; off < 64; off <<= 1) {
                const float ov = __shfl_xor(rv, off);
                const int   oi = __shfl_xor(ridx, off);
                if (ov > rv || (ov == rv && oi < ridx)) { rv = ov; ridx = oi; }
            }
            if (lane == it) out = ridx;
            if (id == ridx) v = -3.4e38f;                          // indices unique
        }
        if (lane < KSEL) topk[(size_t)row * KSEL + lane] = out;
    }
}

// ---------------- Kernel C: projections via split-bf16 MFMA; lo_terms selects 3-term/1-term ----------------
__global__ __launch_bounds__(256)
void proj_split_kernel(const float* __restrict__ X, const unsigned short* __restrict__ Whi,
                       const unsigned short* __restrict__ Wlo, const float* __restrict__ bias,
                       void* __restrict__ outp, const int store_bf16, const int lo_terms)
{
    __shared__ char smem[65536];
    const int tid  = threadIdx.x;
    const int lane = tid & 63;
    const int w    = tid >> 6;
    const int wr   = w >> 1, wc = w & 1;
    const int row0 = blockIdx.x * 128;
    const int col0 = blockIdx.y * 128;

    const f32x4 zero = {0.f, 0.f, 0.f, 0.f};
    f32x4 acc[4][4];
#pragma unroll
    for (int mi = 0; mi < 4; ++mi)
#pragma unroll
        for (int ni = 0; ni < 4; ++ni) acc[mi][ni] = zero;

    const int srow = lane >> 3;
    const int scol = (((lane & 7) ^ srow) << 4);
    const int xr = tid >> 1, xh = tid & 1;

    for (int step = 0; step < 16; ++step) {
        const int kbyte = step << 7;
        const int k0    = step << 6;
        __syncthreads();
#pragma unroll
        for (int i = 0; i < 8; ++i) {
            const int chunk = w + (i << 2);
            if (chunk >= 16 && !lo_terms) continue;
            const int plane = chunk >> 4;
            const int r     = ((chunk & 15) << 3) + srow;
            const unsigned short* Wb = plane ? Wlo : Whi;
            const char* src = (const char*)Wb + (((size_t)(col0 + r)) << 11) + kbyte + scol;
            gload16(src, smem + 32768 + (chunk << 10));
        }
        {
            const float* Xp = X + (size_t)(row0 + xr) * DDIM + k0 + xh * 32;
            float4 xa[8];
#pragma unroll
            for (int i = 0; i < 8; ++i) xa[i] = ((const float4*)Xp)[i];
            const int xbase = xr * 128;
#pragma unroll
            for (int s4 = 0; s4 < 4; ++s4) {
                const float4 a = xa[2 * s4], b = xa[2 * s4 + 1];
                uint4 hw, lw;
                split2(a.x, a.y, hw.x, lw.x);
                split2(a.z, a.w, hw.y, lw.y);
                split2(b.x, b.y, hw.z, lw.z);
                split2(b.z, b.w, hw.w, lw.w);
                const int off = xbase + ((((xh << 2) + s4) ^ (xr & 7)) << 4);
                *(uint4*)(smem + off) = hw;
                if (lo_terms) *(uint4*)(smem + 16384 + off) = lw;
            }
        }
        asm volatile("s_waitcnt vmcnt(0)" ::: "memory");
        __syncthreads();
#pragma unroll
        for (int kk = 0; kk < 2; ++kk) {
            const int cb = (kk << 6) + ((lane >> 4) << 4);
            bf16x8 ah[4], bh[4];
#pragma unroll
            for (int mi = 0; mi < 4; ++mi) {
                const int r = wr * 64 + mi * 16 + (lane & 15);
                ah[mi] = *(const bf16x8*)(smem + r * 128 + (cb ^ ((r & 7) << 4)));
            }
#pragma unroll
            for (int ni = 0; ni < 4; ++ni) {
                const int r = wc * 64 + ni * 16 + (lane & 15);
                bh[ni] = *(const bf16x8*)(smem + 32768 + r * 128 + (cb ^ ((r & 7) << 4)));
            }
#pragma unroll
            for (int mi = 0; mi < 4; ++mi)
#pragma unroll
                for (int ni = 0; ni < 4; ++ni)
                    acc[mi][ni] = __builtin_amdgcn_mfma_f32_16x16x32_bf16(ah[mi], bh[ni], acc[mi][ni], 0, 0, 0);
            if (lo_terms) {
                bf16x8 al[4];
#pragma unroll
                for (int mi = 0; mi < 4; ++mi) {
                    const int r = wr * 64 + mi * 16 + (lane & 15);
                    al[mi] = *(const bf16x8*)(smem + 16384 + r * 128 + (cb ^ ((r & 7) << 4)));
                }
#pragma unroll
                for (int mi = 0; mi < 4; ++mi)
#pragma unroll
                    for (int ni = 0; ni < 4; ++ni)
                        acc[mi][ni] = __builtin_amdgcn_mfma_f32_16x16x32_bf16(al[mi], bh[ni], acc[mi][ni], 0, 0, 0);
                bf16x8 bl[4];
#pragma unroll
                for (int ni = 0; ni < 4; ++ni) {
                    const int r = wc * 64 + ni * 16 + (lane & 15);
                    bl[ni] = *(const bf16x8*)(smem + 49152 + r * 128 + (cb ^ ((r & 7) << 4)));
                }
#pragma unroll
                for (int mi = 0; mi < 4; ++mi)
#pragma unroll
                    for (int ni = 0; ni < 4; ++ni)
                        acc[mi][ni] = __builtin_amdgcn_mfma_f32_16x16x32_bf16(ah[mi], bl[ni], acc[mi][ni], 0, 0, 0);
            }
        }
    }

#pragma unroll
    for (int ni = 0; ni < 4; ++ni) {
        const int col = col0 + wc * 64 + ni * 16 + (lane & 15);
        const float bz = bias[col];
#pragma unroll
        for (int mi = 0; mi < 4; ++mi) {
            const int rbase = row0 + wr * 64 + mi * 16 + ((lane >> 4) << 2);
            const f32x4 v = acc[mi][ni];
#pragma unroll
            for (int j = 0; j < 4; ++j) {
                const float val = v[j] + bz;
                if (store_bf16)
                    ((unsigned short*)outp)[(size_t)(rbase + j) * DDIM + col] = f2bf(val);
                else
                    ((float*)outp)[(size_t)(rbase + j) * DDIM + col] = val;
            }
        }
    }
}

// ---------------- Kernel D: per-token 8-head attention over 16 retrieved slots ----------------
__global__ __launch_bounds__(256)
void attn_kernel(const float* __restrict__ Qp, const __hip_bfloat16* __restrict__ Kp,
                 const __hip_bfloat16* __restrict__ Vp, const int* __restrict__ topk,
                 float* __restrict__ attn_out)
{
    const int t = blockIdx.x;
    __shared__ int   idx_s[KSEL];
    __shared__ float sc_s[4][KSEL];
    if (threadIdx.x < KSEL) idx_s[threadIdx.x] = topk[(size_t)t * KSEL + threadIdx.x];
    __syncthreads();
    const int wv   = threadIdx.x >> 6;
    const int lane = threadIdx.x & 63;
    const int jj = lane >> 2, p = lane & 3;
    const float scale = 0.08838834764831845f;  // 1/sqrt(128)
    const unsigned short* Kpu = (const unsigned short*)Kp;
    const unsigned short* Vpu = (const unsigned short*)Vp;

#pragma unroll 1
    for (int hh = 0; hh < 2; ++hh) {
        const int h = wv * 2 + hh;
        const float* qh = Qp + (size_t)t * DDIM + h * HDIM + p * 32;
        const unsigned short* krow = Kpu + (size_t)idx_s[jj] * DDIM + h * HDIM + p * 32;
        float s = 0.f;
#pragma unroll
        for (int u = 0; u < 32; u += 8) {
            uint4  kv = *(const uint4*)(krow + u);
            float4 qa = *(const float4*)(qh + u);
            float4 qb = *(const float4*)(qh + u + 4);
            const unsigned short* kk = (const unsigned short*)&kv;
            s += bf2f(kk[0]) * qa.x + bf2f(kk[1]) * qa.y + bf2f(kk[2]) * qa.z + bf2f(kk[3]) * qa.w
               + bf2f(kk[4]) * qb.x + bf2f(kk[5]) * qb.y + bf2f(kk[6]) * qb.z + bf2f(kk[7]) * qb.w;
        }
        s += __shfl_xor(s, 1);
        s += __shfl_xor(s, 2);
        if (p == 0) sc_s[wv][jj] = s * scale;
        __syncthreads();
        float mx = -__builtin_inff();
#pragma unroll
        for (int n = 0; n < KSEL; ++n) mx = fmaxf(mx, sc_s[wv][n]);
        float wj[KSEL]; float wsum = 0.f;
#pragma unroll
        for (int n = 0; n < KSEL; ++n) { wj[n] = __expf(sc_s[wv][n] - mx); wsum += wj[n]; }
        const float inv = 1.f / wsum;
        const int d = lane * 2;
        float o0 = 0.f, o1 = 0.f;
#pragma unroll
        for (int n = 0; n < KSEL; ++n) {
            const unsigned int vv = *(const unsigned int*)(Vpu + (size_t)idx_s[n] * DDIM + h * HDIM + d);
            const float w = wj[n] * inv;
            o0 += w * bf2f((unsigned short)(vv & 0xffffu));
            o1 += w * bf2f((unsigned short)(vv >> 16));
        }
        *(float2*)(attn_out + (size_t)t * DDIM + h * HDIM + d) = make_float2(o0, o1);
        __syncthreads();
    }
}

extern "C" void kernel_launch(void* const* d_in, const int* in_sizes, int n_in,
                              void* d_out, int out_size, void* d_ws, size_t ws_size,
                              hipStream_t stream)
{
    const float* queries = (const float*)d_in[0];
    const float* mkeys   = (const float*)d_in[1];
    const float* mvals   = (const float*)d_in[2];
    const float* ipw     = (const float*)d_in[3];
    const float* ipb     = (const float*)d_in[4];
    const float* opw     = (const float*)d_in[5];
    const float* opb     = (const float*)d_in[6];

    char* ws = (char*)d_ws;
    size_t off = 0;
    auto alloc = [&](size_t bytes) -> char* {
        char* p = ws + off;
        off += (bytes + 255) & ~(size_t)255;
        return p;
    };
    unsigned short* Khi  = (unsigned short*)alloc((size_t)MKEYS * DDIM * 2);    // 67.1 MB
    unsigned short* Vp_b = (unsigned short*)alloc((size_t)MKEYS * DDIM * 2);    // 67.1 MB
    unsigned short* Qhi  = (unsigned short*)alloc((size_t)NROWS * DDIM * 2);    // 8.4 MB
    unsigned short* IPhi = (unsigned short*)alloc((size_t)3 * DDIM * DDIM * 2); // 6.3 MB
    unsigned short* IPlo = (unsigned short*)alloc((size_t)3 * DDIM * DDIM * 2); // 6.3 MB
    unsigned short* OPhi = (unsigned short*)alloc((size_t)DDIM * DDIM * 2);     // 2.1 MB
    unsigned short* OPlo = (unsigned short*)alloc((size_t)DDIM * DDIM * 2);     // 2.1 MB
    float* cand_val = (float*)alloc((size_t)NROWS * CANDS_PER_ROW * 4);         // 33.5 MB
    int*   cand_idx = (int*)  alloc((size_t)NROWS * CANDS_PER_ROW * 4);         // 33.5 MB
    int*   cand32   = (int*)  alloc((size_t)NROWS * NCAND * 4);                 // 0.52 MB
    int*   topk     = (int*)  alloc((size_t)NROWS * KSEL * 4);                  // 0.26 MB
    // stream-ordered aliases (total ws ~227 MB):
    float* Qp       = (float*)cand_val;            // cand_val dead after merge
    float* attn_out = (float*)cand_idx;            // cand_idx dead after merge
    __hip_bfloat16* Kp = (__hip_bfloat16*)Khi;     // Khi dead after sims
    __hip_bfloat16* Vp = (__hip_bfloat16*)Vp_b;

    // 0) converts (sims operands, hi-only) + weight splits
    conv_bf16_kernel<<<2048, 256, 0, stream>>>(queries, Qhi, NROWS * DDIM / 4);
    conv_bf16_kernel<<<2048, 256, 0, stream>>>(mkeys, Khi, MKEYS * DDIM / 4);
    split_bf16_kernel<<<1024, 256, 0, stream>>>(ipw, IPhi, IPlo, 3 * DDIM * DDIM / 4);
    split_bf16_kernel<<<512,  256, 0, stream>>>(opw, OPhi, OPlo, DDIM * DDIM / 4);
    // 1) bf16 similarity GEMM + per-keyblock top-16
    sims_mfma_kernel<<<dim3(NROWS / SBM, MKEYS / SBN), 512, 0, stream>>>(Qhi, Khi, cand_val, cand_idx);
    // 2) merge to top-32 candidates (bf16 scores)
    topk_merge_kernel<<<NROWS / 4, 256, 0, stream>>>(cand_val, cand_idx, cand32);
    // 3) exact fp32 rescore -> final top-16
    rescore_kernel<<<NROWS, 256, 0, stream>>>(queries, mkeys, cand32, topk);
    // 4) projections: q (3-term, f32 out), memory bank K/V (1-term, bf16 out)
    proj_split_kernel<<<dim3(NROWS / 128, 8), 256, 0, stream>>>(queries, IPhi, IPlo, ipb, Qp, 0, 1);
    proj_split_kernel<<<dim3(MKEYS / 128, 8), 256, 0, stream>>>(mkeys, IPhi + (size_t)DDIM * DDIM,
                                                                IPlo + (size_t)DDIM * DDIM, ipb + DDIM, Kp, 1, 0);
    proj_split_kernel<<<dim3(MKEYS / 128, 8), 256, 0, stream>>>(mvals, IPhi + 2 * (size_t)DDIM * DDIM,
                                                                IPlo + 2 * (size_t)DDIM * DDIM, ipb + 2 * DDIM, Vp, 1, 0);
    // 5) gather + attention
    attn_kernel<<<NROWS, 256, 0, stream>>>(Qp, Kp, Vp, topk, attn_out);
    // 6) output projection (3-term) -> d_out (f32)
    proj_split_kernel<<<dim3(NROWS / 128, 8), 256, 0, stream>>>(attn_out, OPhi, OPlo, opb, d_out, 0, 1);
}